// Round 3
// baseline (21241.095 us; speedup 1.0000x reference)
//
#include <hip/hip_runtime.h>
#include <math.h>

#define THREADS 256

__device__ __forceinline__ float silu_f(float v) {
    return v / (1.f + __expf(-v));
}

// ---------------------------------------------------------------------------
// Weight transpose: [co][ci][k2] -> [ci][k2][co]  (co contiguous)
// Also used per-group for deform-conv weights.
// ---------------------------------------------------------------------------
struct TEnt { const float* src; int dst; int cin; int cout; int k2; int base; int n; };
struct TTab { TEnt e[24]; int total; };

__global__ __launch_bounds__(THREADS)
void transpose_w_k(TTab t, float* __restrict__ tw) {
    const int i = blockIdx.x * THREADS + threadIdx.x;
    if (i >= t.total) return;
    int j = 0;
    while (i >= t.e[j].base + t.e[j].n) ++j;
    const TEnt e = t.e[j];
    const int local = i - e.base;
    const int co  = local % e.cout;
    const int tmp = local / e.cout;
    const int k   = tmp % e.k2;
    const int ci  = tmp / e.k2;
    tw[e.dst + local] = e.src[(co * e.cin + ci) * e.k2 + k];
}

// ---------------------------------------------------------------------------
// Direct conv2d, stride 1, pad (KS-1)/2, NCHW. PX consecutive x-pixels per
// thread, all COUT channels in registers. Transposed weights staged into LDS
// in CCH-channel chunks with CO_S-padded stride so the co-loop reads are
// ds_read_b128 *broadcasts* (1 LDS instr per 4*PX FMAs).
// W = 1<<lw (power of two). grid.y = batch. Grid is exact (no tail).
// ---------------------------------------------------------------------------
template<int CIN, int COUT, int KS, bool ACT, int CCH = CIN, int PX = 2>
__global__ __launch_bounds__(THREADS, 4)
void conv_k(const float* __restrict__ in, const float* __restrict__ wt,
            const float* __restrict__ bias, float* __restrict__ out,
            int H, int lw, int bs_in, int bs_out)
{
    constexpr int PAD = (KS - 1) / 2;
    constexpr int K2 = KS * KS;
    constexpr int CO_S = (COUT + 3) & ~3;       // pad for 16B-aligned b128
    constexpr int NCH = CIN / CCH;              // CIN % CCH == 0 by choice
    __shared__ float sw[CCH * K2 * CO_S];

    const int W = 1 << lw;
    const int total = H << lw;
    const int idx = (blockIdx.x * THREADS + threadIdx.x) * PX;
    const float* ip0 = in + (size_t)blockIdx.y * bs_in;
    float* op = out + (size_t)blockIdx.y * bs_out;
    const int x0 = idx & (W - 1);
    const int y  = idx >> lw;

    float acc[COUT][PX];
#pragma unroll
    for (int co = 0; co < COUT; ++co) {
        const float b = bias[co];
#pragma unroll
        for (int j = 0; j < PX; ++j) acc[co][j] = b;
    }

    for (int ch = 0; ch < NCH; ++ch) {
        const float* src = wt + (size_t)ch * (CCH * K2 * COUT);
        for (int i = threadIdx.x; i < CCH * K2 * COUT; i += THREADS) {
            const int co = i % COUT;
            const int rest = i / COUT;
            sw[rest * CO_S + co] = src[i];
        }
        __syncthreads();

#pragma unroll 1
        for (int cl = 0; cl < CCH; ++cl) {
            const float* __restrict__ row0 = ip0 + (size_t)(ch * CCH + cl) * total;
#pragma unroll
            for (int ky = 0; ky < KS; ++ky) {
                const int yy = y + ky - PAD;
                const bool vy = (unsigned)yy < (unsigned)H;
                const float* __restrict__ rp = row0 + (yy << lw);
                float r[PX + KS - 1];
#pragma unroll
                for (int t = 0; t < PX + KS - 1; ++t) {
                    const int xx = x0 + t - PAD;
                    r[t] = (vy && (unsigned)xx < (unsigned)W) ? rp[xx] : 0.f;
                }
#pragma unroll
                for (int kx = 0; kx < KS; ++kx) {
                    const float* __restrict__ wr = &sw[(cl * K2 + ky * KS + kx) * CO_S];
#pragma unroll
                    for (int co = 0; co < COUT; ++co) {
                        const float w = wr[co];
#pragma unroll
                        for (int j = 0; j < PX; ++j)
                            acc[co][j] = fmaf(r[kx + j], w, acc[co][j]);
                    }
                }
            }
        }
        if (NCH > 1) __syncthreads();
    }

#pragma unroll
    for (int co = 0; co < COUT; ++co) {
#pragma unroll
        for (int j = 0; j < PX; ++j) {
            float rr = acc[co][j];
            if (ACT) rr = silu_f(rr);
            op[(size_t)co * total + idx + j] = rr;
        }
    }
}

// ---------------------------------------------------------------------------
// DeformConv2d: 3x3, stride 1, pad 1, no bias. groups=2, offset groups=2.
// Per-group transposed weights [c][k][col] staged into LDS (b128 broadcast).
// offset layout: [OG=2][K=9][2(dy,dx)][H][W]
// ---------------------------------------------------------------------------
template<int CIN, int COUT>
__global__ __launch_bounds__(THREADS, 4)
void dconv_k(const float* __restrict__ in, const float* __restrict__ off,
             const float* __restrict__ twg0, const float* __restrict__ twg1,
             float* __restrict__ out,
             int H, int lw, int bs_in, int bs_off, int bs_out)
{
    constexpr int K = 9;
    constexpr int OG = 2;
    constexpr int COG = CIN / OG;
    constexpr int COUTG = COUT / 2;
    constexpr int NWG = COG * K * COUTG;
    __shared__ float sw[2 * NWG];
    for (int i = threadIdx.x; i < 2 * NWG; i += THREADS)
        sw[i] = (i < NWG) ? twg0[i] : twg1[i - NWG];
    __syncthreads();

    const int W = 1 << lw;
    const int total = H << lw;
    const int idx = blockIdx.x * THREADS + threadIdx.x;
    const float* ip0 = in + (size_t)blockIdx.y * bs_in;
    const float* offp = off + (size_t)blockIdx.y * bs_off;
    float* op = out + (size_t)blockIdx.y * bs_out;
    const int x = idx & (W - 1);
    const int y = idx >> lw;

    float acc[COUT];
#pragma unroll
    for (int co = 0; co < COUT; ++co) acc[co] = 0.f;

#pragma unroll
    for (int og = 0; og < OG; ++og) {
#pragma unroll
        for (int k = 0; k < K; ++k) {
            const int ki = k / 3 - 1;
            const int kj = k % 3 - 1;
            const float dy = offp[(size_t)(((og * K + k) * 2 + 0)) * total + idx];
            const float dx = offp[(size_t)(((og * K + k) * 2 + 1)) * total + idx];
            const float py = dy + (float)(y + ki);
            const float px = dx + (float)(x + kj);
            const float y0f = floorf(py), x0f = floorf(px);
            const float ly = py - y0f, lx = px - x0f;
            const int y0 = (int)y0f, x0 = (int)x0f;
            const int y1 = y0 + 1, x1 = x0 + 1;
            const bool vy0 = (unsigned)y0 < (unsigned)H;
            const bool vy1 = (unsigned)y1 < (unsigned)H;
            const bool vx0 = (unsigned)x0 < (unsigned)W;
            const bool vx1 = (unsigned)x1 < (unsigned)W;
            const int cy0 = min(max(y0, 0), H - 1), cy1 = min(max(y1, 0), H - 1);
            const int cx0 = min(max(x0, 0), W - 1), cx1 = min(max(x1, 0), W - 1);
            const int i00 = (cy0 << lw) + cx0, i01 = (cy0 << lw) + cx1;
            const int i10 = (cy1 << lw) + cx0, i11 = (cy1 << lw) + cx1;
            const float f00 = (vy0 && vx0) ? (1.f - ly) * (1.f - lx) : 0.f;
            const float f01 = (vy0 && vx1) ? (1.f - ly) * lx : 0.f;
            const float f10 = (vy1 && vx0) ? ly * (1.f - lx) : 0.f;
            const float f11 = (vy1 && vx1) ? ly * lx : 0.f;
            const float* swg = &sw[og * NWG];
#pragma unroll
            for (int c = 0; c < COG; ++c) {
                const float* __restrict__ ip = ip0 + (size_t)(og * COG + c) * total;
                const float v = f00 * ip[i00] + f01 * ip[i01]
                              + f10 * ip[i10] + f11 * ip[i11];
                const float* __restrict__ wr = &swg[(c * K + k) * COUTG];
#pragma unroll
                for (int col = 0; col < COUTG; ++col)
                    acc[og * COUTG + col] = fmaf(v, wr[col], acc[og * COUTG + col]);
            }
        }
    }

#pragma unroll
    for (int co = 0; co < COUT; ++co)
        op[(size_t)co * total + idx] = acc[co];
}

// 2x2 average pool. n = C*Ho*Wo, lt = log2(Ho*Wo), lwo = log2(Wo).
__global__ __launch_bounds__(THREADS)
void avgpool_k(const float* __restrict__ in, float* __restrict__ out,
               int n, int lt, int lwo, int bsi, int bso)
{
    const int idx = blockIdx.x * THREADS + threadIdx.x;
    if (idx >= n) return;
    const float* ip0 = in + (size_t)blockIdx.y * bsi;
    float* op = out + (size_t)blockIdx.y * bso;
    const int c = idx >> lt;
    const int r = idx & ((1 << lt) - 1);
    const int oy = r >> lwo;
    const int ox = r & ((1 << lwo) - 1);
    const int Wi = 2 << lwo;
    const float* ip = ip0 + ((size_t)c << (lt + 2)) + ((size_t)(2 * oy) << (lwo + 1)) + 2 * ox;
    op[idx] = 0.25f * (ip[0] + ip[1] + ip[Wi] + ip[Wi + 1]);
}

// Bilinear 2x upsample, align_corners=True.
__global__ __launch_bounds__(THREADS)
void up2x_k(const float* __restrict__ in, float* __restrict__ out,
            int n, int lt, int lwo, int Hin, int bsi, int bso)
{
    const int idx = blockIdx.x * THREADS + threadIdx.x;
    if (idx >= n) return;
    const float* ip0 = in + (size_t)blockIdx.y * bsi;
    float* op = out + (size_t)blockIdx.y * bso;
    const int c = idx >> lt;
    const int r = idx & ((1 << lt) - 1);
    const int oy = r >> lwo;
    const int ox = r & ((1 << lwo) - 1);
    const int W = 1 << (lwo - 1);
    const int H = Hin;
    const float s = (float)(H - 1) / (float)(2 * H - 1);
    const float fy = (float)oy * s;
    const float fx = (float)ox * s;
    const int y0 = (int)fy;
    const int x0 = (int)fx;
    const int y1 = min(y0 + 1, H - 1);
    const int x1 = min(x0 + 1, W - 1);
    const float wy = fy - (float)y0;
    const float wx = fx - (float)x0;
    const float* ip = ip0 + ((size_t)c << (lt - 2));
    const float v00 = ip[y0 * W + x0], v01 = ip[y0 * W + x1];
    const float v10 = ip[y1 * W + x0], v11 = ip[y1 * W + x1];
    op[idx] = (v00 * (1.f - wy) + v10 * wy) * (1.f - wx)
            + (v01 * (1.f - wy) + v11 * wy) * wx;
}

// strided batched d2d copy (float4 granularity)
__global__ __launch_bounds__(THREADS)
void copy_k(float4* __restrict__ dst, const float4* __restrict__ src,
            int n4, int bsd, int bss)
{
    const int i = blockIdx.x * THREADS + threadIdx.x;
    if (i >= n4) return;
    dst[(size_t)blockIdx.y * bsd + i] = src[(size_t)blockIdx.y * bss + i];
}

// ---------------------------------------------------------------------------

extern "C" void kernel_launch(void* const* d_in, const int* in_sizes, int n_in,
                              void* d_out, int out_size, void* d_ws, size_t ws_size,
                              hipStream_t stream) {
    const float* x      = (const float*)d_in[0];
    const float* eo1_b1 = (const float*)d_in[2];
    const float* eo1_b2 = (const float*)d_in[4];
    const float* c1d_b1 = (const float*)d_in[7];
    const float* c1d_b2 = (const float*)d_in[9];
    const float* eo2_b1 = (const float*)d_in[11];
    const float* eo2_b2 = (const float*)d_in[13];
    const float* c2d_b1 = (const float*)d_in[16];
    const float* c2d_b2 = (const float*)d_in[18];
    const float* eo3_b1 = (const float*)d_in[20];
    const float* eo3_b2 = (const float*)d_in[22];
    const float* c3d_b1 = (const float*)d_in[25];
    const float* c3d_b2 = (const float*)d_in[27];
    const float* up2_b  = (const float*)d_in[29];
    const float* c2u_b1 = (const float*)d_in[31];
    const float* c2u_b2 = (const float*)d_in[33];
    const float* up1_b  = (const float*)d_in[35];
    const float* c1u_b1 = (const float*)d_in[37];
    const float* c1u_b2 = (const float*)d_in[39];

    float* out = (float*)d_out;
    float* wsf = (float*)d_ws;

    constexpr int H1 = 512, A1 = H1 * H1;
    constexpr int H2 = 256, A2 = H2 * H2;
    constexpr int H3 = 128, A3 = H3 * H3;
    constexpr int TW_FLOATS = 81920;
    constexpr int SLOT = 70 * A1 + 24 * A2;

    // ---- transposed-weight table: 18 convs + 6 dconv groups ----
    // conv entries 0..17
    const int widx[18]  = {1, 3, 6, 8, 10, 12, 15, 17, 19, 21, 24, 26, 28, 30, 32, 34, 36, 38};
    const int wcin[18]  = {4, 18, 2, 4, 8, 18, 8, 12, 16, 18, 16, 14, 12, 28, 16, 8, 16, 8};
    const int wcout[18] = {18, 36, 4, 8, 18, 36, 12, 16, 18, 36, 14, 12, 12, 16, 8, 8, 8, 2};
    const int wk2[18]   = {25, 25, 9, 9, 25, 25, 9, 9, 25, 25, 9, 9, 9, 9, 9, 9, 9, 9};
    TTab tab;
    const float* tw[24];
    int off = 0, base = 0;
    for (int i = 0; i < 18; ++i) {
        const int n = wcin[i] * wcout[i] * wk2[i];
        tab.e[i].src = (const float*)d_in[widx[i]];
        tab.e[i].dst = off; tab.e[i].cin = wcin[i]; tab.e[i].cout = wcout[i];
        tab.e[i].k2 = wk2[i]; tab.e[i].base = base; tab.e[i].n = n;
        tw[i] = wsf + off;
        off = (off + n + 63) & ~63;
        base += n;
    }
    // dconv entries 18..23: {dcw idx, COUTG, CPG} per group
    const int didx[3]   = {5, 14, 23};
    const int dcoutg[3] = {1, 4, 8};
    const int dcpg[3]   = {2, 4, 8};
    for (int i = 0; i < 3; ++i) {
        for (int g = 0; g < 2; ++g) {
            const int e = 18 + 2 * i + g;
            const int n = dcoutg[i] * dcpg[i] * 9;
            tab.e[e].src = (const float*)d_in[didx[i]] + (size_t)g * n;
            tab.e[e].dst = off; tab.e[e].cin = dcpg[i]; tab.e[e].cout = dcoutg[i];
            tab.e[e].k2 = 9; tab.e[e].base = base; tab.e[e].n = n;
            tw[e] = wsf + off;
            off = (off + n + 63) & ~63;
            base += n;
        }
    }
    tab.total = base;
    transpose_w_k<<<(base + THREADS - 1) / THREADS, THREADS, 0, stream>>>(tab, wsf);

    int B = 4;
    while (B > 1 && ws_size < ((size_t)TW_FLOATS + (size_t)B * SLOT) * sizeof(float)) B >>= 1;

    auto run_all = [&](int Bc, float* slot, int SB,
                       const float* xin, int xbs, float* outp, int obs) {
        float* S0 = slot;                // 36*A1
        float* S1 = S0 + 36 * A1;        // 18*A1
        float* S2 = S1 + 18 * A1;        //  8*A1
        float* P  = S2 + 8 * A1;         //  8*A2
        float* L1 = P + 8 * A2;          //  8*A1  (conv1_d skip)
        float* L2 = L1 + 8 * A1;         // 16*A2  (conv2_d skip)
        auto g2 = [&](int n) { return dim3((n + 2 * THREADS - 1) / (2 * THREADS), Bc); };
        auto g1 = [&](int n) { return dim3((n + THREADS - 1) / THREADS, Bc); };

        // ---- level 1 down ----
        conv_k<4, 18, 5, false><<<g2(A1), THREADS, 0, stream>>>(xin, tw[0], eo1_b1, S1, H1, 9, xbs, SB);
        conv_k<18, 36, 5, false, 6><<<g2(A1), THREADS, 0, stream>>>(S1, tw[1], eo1_b2, S0, H1, 9, SB, SB);
        dconv_k<4, 2><<<g1(A1), THREADS, 0, stream>>>(xin, S0, tw[18], tw[19], S2, H1, 9, xbs, SB, SB);
        conv_k<2, 4, 3, true><<<g2(A1), THREADS, 0, stream>>>(S2, tw[2], c1d_b1, S1, H1, 9, SB, SB);
        conv_k<4, 8, 3, true><<<g2(A1), THREADS, 0, stream>>>(S1, tw[3], c1d_b2, L1, H1, 9, SB, SB);
        avgpool_k<<<g1(8 * A2), THREADS, 0, stream>>>(L1, P, 8 * A2, 16, 8, SB, SB);

        // ---- level 2 down ----
        conv_k<8, 18, 5, false><<<g2(A2), THREADS, 0, stream>>>(P, tw[4], eo2_b1, S1, H2, 8, SB, SB);
        conv_k<18, 36, 5, false, 6><<<g2(A2), THREADS, 0, stream>>>(S1, tw[5], eo2_b2, S0, H2, 8, SB, SB);
        dconv_k<8, 8><<<g1(A2), THREADS, 0, stream>>>(P, S0, tw[20], tw[21], S2, H2, 8, SB, SB, SB);
        conv_k<8, 12, 3, true><<<g2(A2), THREADS, 0, stream>>>(S2, tw[6], c2d_b1, S1, H2, 8, SB, SB);
        conv_k<12, 16, 3, true><<<g2(A2), THREADS, 0, stream>>>(S1, tw[7], c2d_b2, L2, H2, 8, SB, SB);
        avgpool_k<<<g1(16 * A3), THREADS, 0, stream>>>(L2, P, 16 * A3, 14, 7, SB, SB);

        // ---- level 3 (bottleneck) ----
        conv_k<16, 18, 5, false, 8><<<g2(A3), THREADS, 0, stream>>>(P, tw[8], eo3_b1, S1, H3, 7, SB, SB);
        conv_k<18, 36, 5, false, 6><<<g2(A3), THREADS, 0, stream>>>(S1, tw[9], eo3_b2, S0, H3, 7, SB, SB);
        dconv_k<16, 16><<<g1(A3), THREADS, 0, stream>>>(P, S0, tw[22], tw[23], S2, H3, 7, SB, SB, SB);
        conv_k<16, 14, 3, true><<<g2(A3), THREADS, 0, stream>>>(S2, tw[10], c3d_b1, S1, H3, 7, SB, SB);
        conv_k<14, 12, 3, true><<<g2(A3), THREADS, 0, stream>>>(S1, tw[11], c3d_b2, S2, H3, 7, SB, SB);

        // ---- up path level 2 ----
        up2x_k<<<g1(12 * A2), THREADS, 0, stream>>>(S2, S0, 12 * A2, 16, 8, H3, SB, SB);
        conv_k<12, 12, 3, true><<<g2(A2), THREADS, 0, stream>>>(S0, tw[12], up2_b, S1, H2, 8, SB, SB);
        copy_k<<<g1(4 * A2), THREADS, 0, stream>>>((float4*)(S1 + 12 * A2), (const float4*)L2,
                                                   4 * A2, SB / 4, SB / 4);
        conv_k<28, 16, 3, true><<<g2(A2), THREADS, 0, stream>>>(S1, tw[13], c2u_b1, S0, H2, 8, SB, SB);
        conv_k<16, 8, 3, true><<<g2(A2), THREADS, 0, stream>>>(S0, tw[14], c2u_b2, S2, H2, 8, SB, SB);

        // ---- up path level 1 ----
        up2x_k<<<g1(8 * A1), THREADS, 0, stream>>>(S2, S0, 8 * A1, 18, 9, H2, SB, SB);
        conv_k<8, 8, 3, true><<<g2(A1), THREADS, 0, stream>>>(S0, tw[15], up1_b, S1, H1, 9, SB, SB);
        copy_k<<<g1(2 * A1), THREADS, 0, stream>>>((float4*)(S1 + 8 * A1), (const float4*)L1,
                                                   2 * A1, SB / 4, SB / 4);
        conv_k<16, 8, 3, true><<<g2(A1), THREADS, 0, stream>>>(S1, tw[16], c1u_b1, S0, H1, 9, SB, SB);
        conv_k<8, 2, 3, true><<<g2(A1), THREADS, 0, stream>>>(S0, tw[17], c1u_b2, outp, H1, 9, SB, obs);
    };

    for (int g = 0; g < 4; g += B)
        run_all(B, wsf + TW_FLOATS, SLOT,
                x + (size_t)g * 4 * A1, 4 * A1,
                out + (size_t)g * 2 * A1, 2 * A1);
}

// Round 4
// 8783.661 us; speedup vs baseline: 2.4183x; 2.4183x over previous
//
#include <hip/hip_runtime.h>
#include <math.h>

#define THREADS 256

__device__ __forceinline__ float silu_f(float v) {
    return v / (1.f + __expf(-v));
}

// ---------------------------------------------------------------------------
// Weight transpose: [co][ci][k2] -> [ci][k2][co]  (co contiguous)
// Also used per-group for deform-conv weights.
// ---------------------------------------------------------------------------
struct TEnt { const float* src; int dst; int cin; int cout; int k2; int base; int n; };
struct TTab { TEnt e[24]; int total; };

__global__ __launch_bounds__(THREADS)
void transpose_w_k(TTab t, float* __restrict__ tw) {
    const int i = blockIdx.x * THREADS + threadIdx.x;
    if (i >= t.total) return;
    int j = 0;
    while (i >= t.e[j].base + t.e[j].n) ++j;
    const TEnt e = t.e[j];
    const int local = i - e.base;
    const int co  = local % e.cout;
    const int tmp = local / e.cout;
    const int k   = tmp % e.k2;
    const int ci  = tmp / e.k2;
    tw[e.dst + local] = e.src[(co * e.cin + ci) * e.k2 + k];
}

// ---------------------------------------------------------------------------
// Direct conv2d, stride 1, pad (KS-1)/2, NCHW. PX=2 consecutive x-pixels per
// thread, all COUT channels in registers. Transposed weights staged into LDS
// in CCH-channel chunks with CO_S-padded stride so the co-loop reads are
// ds_read_b128 broadcasts. Input rows loaded as aligned float2, outputs
// stored as float2 (x0 even). W = 1<<lw. grid.y = batch. Grid exact.
// NOTE: no min-waves hint — acc[COUT][2] must live in VGPRs (round-3 spill).
// ---------------------------------------------------------------------------
template<int CIN, int COUT, int KS, bool ACT, int CCH = CIN>
__global__ __launch_bounds__(THREADS)
void conv_k(const float* __restrict__ in, const float* __restrict__ wt,
            const float* __restrict__ bias, float* __restrict__ out,
            int H, int lw, int bs_in, int bs_out)
{
    constexpr int PAD = (KS - 1) / 2;
    constexpr int K2 = KS * KS;
    constexpr int PX = 2;
    constexpr int CO_S = (COUT + 3) & ~3;       // pad for 16B-aligned b128
    constexpr int NCH = CIN / CCH;
    __shared__ float sw[CCH * K2 * CO_S];

    const int W = 1 << lw;
    const int total = H << lw;
    const int idx = (blockIdx.x * THREADS + threadIdx.x) * PX;
    const float* ip0 = in + (size_t)blockIdx.y * bs_in;
    float* op = out + (size_t)blockIdx.y * bs_out;
    const int x0 = idx & (W - 1);               // even
    const int y  = idx >> lw;

    float acc[COUT][PX];
#pragma unroll
    for (int co = 0; co < COUT; ++co) {
        const float b = bias[co];
#pragma unroll
        for (int j = 0; j < PX; ++j) acc[co][j] = b;
    }

    for (int ch = 0; ch < NCH; ++ch) {
        const float* src = wt + (size_t)ch * (CCH * K2 * COUT);
        for (int i = threadIdx.x; i < CCH * K2 * COUT; i += THREADS) {
            const int co = i % COUT;
            const int rest = i / COUT;
            sw[rest * CO_S + co] = src[i];
        }
        __syncthreads();

#pragma unroll 1
        for (int cl = 0; cl < CCH; ++cl) {
            const float* __restrict__ row0 = ip0 + (size_t)(ch * CCH + cl) * total;
#pragma unroll
            for (int ky = 0; ky < KS; ++ky) {
                const int yy = y + ky - PAD;
                const bool vy = (unsigned)yy < (unsigned)H;
                const float* __restrict__ rp = row0 + (yy << lw);
                float r[PX + KS - 1];
                if (KS == 5) {
                    const bool vlo = vy && (x0 >= 2);
                    const bool vhi = vy && (x0 + 3 < W);
                    float2 a = make_float2(0.f, 0.f), b = a, c = a;
                    if (vlo) a = *reinterpret_cast<const float2*>(rp + x0 - 2);
                    if (vy)  b = *reinterpret_cast<const float2*>(rp + x0);
                    if (vhi) c = *reinterpret_cast<const float2*>(rp + x0 + 2);
                    r[0] = a.x; r[1] = a.y; r[2] = b.x; r[3] = b.y; r[4] = c.x; r[5] = c.y;
                } else {
                    float2 b = make_float2(0.f, 0.f);
                    if (vy) b = *reinterpret_cast<const float2*>(rp + x0);
                    r[1] = b.x; r[2] = b.y;
                    r[0] = (vy && x0 >= 1) ? rp[x0 - 1] : 0.f;
                    r[3] = (vy && x0 + 2 < W) ? rp[x0 + 2] : 0.f;
                }
#pragma unroll
                for (int kx = 0; kx < KS; ++kx) {
                    const float* __restrict__ wr = &sw[(cl * K2 + ky * KS + kx) * CO_S];
#pragma unroll
                    for (int co = 0; co < COUT; ++co) {
                        const float w = wr[co];
#pragma unroll
                        for (int j = 0; j < PX; ++j)
                            acc[co][j] = fmaf(r[kx + j], w, acc[co][j]);
                    }
                }
            }
        }
        if (NCH > 1) __syncthreads();
    }

#pragma unroll
    for (int co = 0; co < COUT; ++co) {
        float2 v;
        v.x = ACT ? silu_f(acc[co][0]) : acc[co][0];
        v.y = ACT ? silu_f(acc[co][1]) : acc[co][1];
        *reinterpret_cast<float2*>(op + (size_t)co * total + idx) = v;
    }
}

// ---------------------------------------------------------------------------
// DeformConv2d: 3x3, stride 1, pad 1, no bias. groups=2, offset groups=2.
// Per-group transposed weights [c][k][col] staged into LDS (b128 broadcast).
// offset layout: [OG=2][K=9][2(dy,dx)][H][W]
// ---------------------------------------------------------------------------
template<int CIN, int COUT>
__global__ __launch_bounds__(THREADS)
void dconv_k(const float* __restrict__ in, const float* __restrict__ off,
             const float* __restrict__ twg0, const float* __restrict__ twg1,
             float* __restrict__ out,
             int H, int lw, int bs_in, int bs_off, int bs_out)
{
    constexpr int K = 9;
    constexpr int OG = 2;
    constexpr int COG = CIN / OG;
    constexpr int COUTG = COUT / 2;
    constexpr int NWG = COG * K * COUTG;
    __shared__ float sw[2 * NWG];
    for (int i = threadIdx.x; i < 2 * NWG; i += THREADS)
        sw[i] = (i < NWG) ? twg0[i] : twg1[i - NWG];
    __syncthreads();

    const int W = 1 << lw;
    const int total = H << lw;
    const int idx = blockIdx.x * THREADS + threadIdx.x;
    const float* ip0 = in + (size_t)blockIdx.y * bs_in;
    const float* offp = off + (size_t)blockIdx.y * bs_off;
    float* op = out + (size_t)blockIdx.y * bs_out;
    const int x = idx & (W - 1);
    const int y = idx >> lw;

    float acc[COUT];
#pragma unroll
    for (int co = 0; co < COUT; ++co) acc[co] = 0.f;

#pragma unroll
    for (int og = 0; og < OG; ++og) {
#pragma unroll
        for (int k = 0; k < K; ++k) {
            const int ki = k / 3 - 1;
            const int kj = k % 3 - 1;
            const float dy = offp[(size_t)(((og * K + k) * 2 + 0)) * total + idx];
            const float dx = offp[(size_t)(((og * K + k) * 2 + 1)) * total + idx];
            const float py = dy + (float)(y + ki);
            const float px = dx + (float)(x + kj);
            const float y0f = floorf(py), x0f = floorf(px);
            const float ly = py - y0f, lx = px - x0f;
            const int y0 = (int)y0f, x0 = (int)x0f;
            const int y1 = y0 + 1, x1 = x0 + 1;
            const bool vy0 = (unsigned)y0 < (unsigned)H;
            const bool vy1 = (unsigned)y1 < (unsigned)H;
            const bool vx0 = (unsigned)x0 < (unsigned)W;
            const bool vx1 = (unsigned)x1 < (unsigned)W;
            const int cy0 = min(max(y0, 0), H - 1), cy1 = min(max(y1, 0), H - 1);
            const int cx0 = min(max(x0, 0), W - 1), cx1 = min(max(x1, 0), W - 1);
            const int i00 = (cy0 << lw) + cx0, i01 = (cy0 << lw) + cx1;
            const int i10 = (cy1 << lw) + cx0, i11 = (cy1 << lw) + cx1;
            const float f00 = (vy0 && vx0) ? (1.f - ly) * (1.f - lx) : 0.f;
            const float f01 = (vy0 && vx1) ? (1.f - ly) * lx : 0.f;
            const float f10 = (vy1 && vx0) ? ly * (1.f - lx) : 0.f;
            const float f11 = (vy1 && vx1) ? ly * lx : 0.f;
            const float* swg = &sw[og * NWG];
#pragma unroll
            for (int c = 0; c < COG; ++c) {
                const float* __restrict__ ip = ip0 + (size_t)(og * COG + c) * total;
                const float v = f00 * ip[i00] + f01 * ip[i01]
                              + f10 * ip[i10] + f11 * ip[i11];
                const float* __restrict__ wr = &swg[(c * K + k) * COUTG];
#pragma unroll
                for (int col = 0; col < COUTG; ++col)
                    acc[og * COUTG + col] = fmaf(v, wr[col], acc[og * COUTG + col]);
            }
        }
    }

#pragma unroll
    for (int co = 0; co < COUT; ++co)
        op[(size_t)co * total + idx] = acc[co];
}

// 2x2 average pool. n = C*Ho*Wo, lt = log2(Ho*Wo), lwo = log2(Wo).
__global__ __launch_bounds__(THREADS)
void avgpool_k(const float* __restrict__ in, float* __restrict__ out,
               int n, int lt, int lwo, int bsi, int bso)
{
    const int idx = blockIdx.x * THREADS + threadIdx.x;
    if (idx >= n) return;
    const float* ip0 = in + (size_t)blockIdx.y * bsi;
    float* op = out + (size_t)blockIdx.y * bso;
    const int c = idx >> lt;
    const int r = idx & ((1 << lt) - 1);
    const int oy = r >> lwo;
    const int ox = r & ((1 << lwo) - 1);
    const int Wi = 2 << lwo;
    const float* ip = ip0 + ((size_t)c << (lt + 2)) + ((size_t)(2 * oy) << (lwo + 1)) + 2 * ox;
    const float2 t = *reinterpret_cast<const float2*>(ip);
    const float2 b = *reinterpret_cast<const float2*>(ip + Wi);
    op[idx] = 0.25f * (t.x + t.y + b.x + b.y);
}

// Bilinear 2x upsample, align_corners=True.
__global__ __launch_bounds__(THREADS)
void up2x_k(const float* __restrict__ in, float* __restrict__ out,
            int n, int lt, int lwo, int Hin, int bsi, int bso)
{
    const int idx = blockIdx.x * THREADS + threadIdx.x;
    if (idx >= n) return;
    const float* ip0 = in + (size_t)blockIdx.y * bsi;
    float* op = out + (size_t)blockIdx.y * bso;
    const int c = idx >> lt;
    const int r = idx & ((1 << lt) - 1);
    const int oy = r >> lwo;
    const int ox = r & ((1 << lwo) - 1);
    const int W = 1 << (lwo - 1);
    const int H = Hin;
    const float s = (float)(H - 1) / (float)(2 * H - 1);
    const float fy = (float)oy * s;
    const float fx = (float)ox * s;
    const int y0 = (int)fy;
    const int x0 = (int)fx;
    const int y1 = min(y0 + 1, H - 1);
    const int x1 = min(x0 + 1, W - 1);
    const float wy = fy - (float)y0;
    const float wx = fx - (float)x0;
    const float* ip = ip0 + ((size_t)c << (lt - 2));
    const float v00 = ip[y0 * W + x0], v01 = ip[y0 * W + x1];
    const float v10 = ip[y1 * W + x0], v11 = ip[y1 * W + x1];
    op[idx] = (v00 * (1.f - wy) + v10 * wy) * (1.f - wx)
            + (v01 * (1.f - wy) + v11 * wy) * wx;
}

// strided batched d2d copy (float4 granularity)
__global__ __launch_bounds__(THREADS)
void copy_k(float4* __restrict__ dst, const float4* __restrict__ src,
            int n4, int bsd, int bss)
{
    const int i = blockIdx.x * THREADS + threadIdx.x;
    if (i >= n4) return;
    dst[(size_t)blockIdx.y * bsd + i] = src[(size_t)blockIdx.y * bss + i];
}

// ---------------------------------------------------------------------------

extern "C" void kernel_launch(void* const* d_in, const int* in_sizes, int n_in,
                              void* d_out, int out_size, void* d_ws, size_t ws_size,
                              hipStream_t stream) {
    const float* x      = (const float*)d_in[0];
    const float* eo1_b1 = (const float*)d_in[2];
    const float* eo1_b2 = (const float*)d_in[4];
    const float* c1d_b1 = (const float*)d_in[7];
    const float* c1d_b2 = (const float*)d_in[9];
    const float* eo2_b1 = (const float*)d_in[11];
    const float* eo2_b2 = (const float*)d_in[13];
    const float* c2d_b1 = (const float*)d_in[16];
    const float* c2d_b2 = (const float*)d_in[18];
    const float* eo3_b1 = (const float*)d_in[20];
    const float* eo3_b2 = (const float*)d_in[22];
    const float* c3d_b1 = (const float*)d_in[25];
    const float* c3d_b2 = (const float*)d_in[27];
    const float* up2_b  = (const float*)d_in[29];
    const float* c2u_b1 = (const float*)d_in[31];
    const float* c2u_b2 = (const float*)d_in[33];
    const float* up1_b  = (const float*)d_in[35];
    const float* c1u_b1 = (const float*)d_in[37];
    const float* c1u_b2 = (const float*)d_in[39];

    float* out = (float*)d_out;
    float* wsf = (float*)d_ws;

    constexpr int H1 = 512, A1 = H1 * H1;
    constexpr int H2 = 256, A2 = H2 * H2;
    constexpr int H3 = 128, A3 = H3 * H3;
    constexpr int TW_FLOATS = 81920;
    constexpr int SLOT = 70 * A1 + 24 * A2;

    // ---- transposed-weight table: 18 convs + 6 dconv groups ----
    const int widx[18]  = {1, 3, 6, 8, 10, 12, 15, 17, 19, 21, 24, 26, 28, 30, 32, 34, 36, 38};
    const int wcin[18]  = {4, 18, 2, 4, 8, 18, 8, 12, 16, 18, 16, 14, 12, 28, 16, 8, 16, 8};
    const int wcout[18] = {18, 36, 4, 8, 18, 36, 12, 16, 18, 36, 14, 12, 12, 16, 8, 8, 8, 2};
    const int wk2[18]   = {25, 25, 9, 9, 25, 25, 9, 9, 25, 25, 9, 9, 9, 9, 9, 9, 9, 9};
    TTab tab;
    const float* tw[24];
    int off = 0, base = 0;
    for (int i = 0; i < 18; ++i) {
        const int n = wcin[i] * wcout[i] * wk2[i];
        tab.e[i].src = (const float*)d_in[widx[i]];
        tab.e[i].dst = off; tab.e[i].cin = wcin[i]; tab.e[i].cout = wcout[i];
        tab.e[i].k2 = wk2[i]; tab.e[i].base = base; tab.e[i].n = n;
        tw[i] = wsf + off;
        off = (off + n + 63) & ~63;
        base += n;
    }
    const int didx[3]   = {5, 14, 23};
    const int dcoutg[3] = {1, 4, 8};
    const int dcpg[3]   = {2, 4, 8};
    for (int i = 0; i < 3; ++i) {
        for (int g = 0; g < 2; ++g) {
            const int e = 18 + 2 * i + g;
            const int n = dcoutg[i] * dcpg[i] * 9;
            tab.e[e].src = (const float*)d_in[didx[i]] + (size_t)g * n;
            tab.e[e].dst = off; tab.e[e].cin = dcpg[i]; tab.e[e].cout = dcoutg[i];
            tab.e[e].k2 = 9; tab.e[e].base = base; tab.e[e].n = n;
            tw[e] = wsf + off;
            off = (off + n + 63) & ~63;
            base += n;
        }
    }
    tab.total = base;
    transpose_w_k<<<(base + THREADS - 1) / THREADS, THREADS, 0, stream>>>(tab, wsf);

    int B = 4;
    while (B > 1 && ws_size < ((size_t)TW_FLOATS + (size_t)B * SLOT) * sizeof(float)) B >>= 1;

    auto run_all = [&](int Bc, float* slot, int SB,
                       const float* xin, int xbs, float* outp, int obs) {
        float* S0 = slot;                // 36*A1
        float* S1 = S0 + 36 * A1;        // 18*A1
        float* S2 = S1 + 18 * A1;        //  8*A1
        float* P  = S2 + 8 * A1;         //  8*A2
        float* L1 = P + 8 * A2;          //  8*A1  (conv1_d skip)
        float* L2 = L1 + 8 * A1;         // 16*A2  (conv2_d skip)
        auto g2 = [&](int n) { return dim3((n + 2 * THREADS - 1) / (2 * THREADS), Bc); };
        auto g1 = [&](int n) { return dim3((n + THREADS - 1) / THREADS, Bc); };

        // ---- level 1 down ----
        conv_k<4, 18, 5, false><<<g2(A1), THREADS, 0, stream>>>(xin, tw[0], eo1_b1, S1, H1, 9, xbs, SB);
        conv_k<18, 36, 5, false, 6><<<g2(A1), THREADS, 0, stream>>>(S1, tw[1], eo1_b2, S0, H1, 9, SB, SB);
        dconv_k<4, 2><<<g1(A1), THREADS, 0, stream>>>(xin, S0, tw[18], tw[19], S2, H1, 9, xbs, SB, SB);
        conv_k<2, 4, 3, true><<<g2(A1), THREADS, 0, stream>>>(S2, tw[2], c1d_b1, S1, H1, 9, SB, SB);
        conv_k<4, 8, 3, true><<<g2(A1), THREADS, 0, stream>>>(S1, tw[3], c1d_b2, L1, H1, 9, SB, SB);
        avgpool_k<<<g1(8 * A2), THREADS, 0, stream>>>(L1, P, 8 * A2, 16, 8, SB, SB);

        // ---- level 2 down ----
        conv_k<8, 18, 5, false><<<g2(A2), THREADS, 0, stream>>>(P, tw[4], eo2_b1, S1, H2, 8, SB, SB);
        conv_k<18, 36, 5, false, 6><<<g2(A2), THREADS, 0, stream>>>(S1, tw[5], eo2_b2, S0, H2, 8, SB, SB);
        dconv_k<8, 8><<<g1(A2), THREADS, 0, stream>>>(P, S0, tw[20], tw[21], S2, H2, 8, SB, SB, SB);
        conv_k<8, 12, 3, true><<<g2(A2), THREADS, 0, stream>>>(S2, tw[6], c2d_b1, S1, H2, 8, SB, SB);
        conv_k<12, 16, 3, true><<<g2(A2), THREADS, 0, stream>>>(S1, tw[7], c2d_b2, L2, H2, 8, SB, SB);
        avgpool_k<<<g1(16 * A3), THREADS, 0, stream>>>(L2, P, 16 * A3, 14, 7, SB, SB);

        // ---- level 3 (bottleneck) ----
        conv_k<16, 18, 5, false, 8><<<g2(A3), THREADS, 0, stream>>>(P, tw[8], eo3_b1, S1, H3, 7, SB, SB);
        conv_k<18, 36, 5, false, 6><<<g2(A3), THREADS, 0, stream>>>(S1, tw[9], eo3_b2, S0, H3, 7, SB, SB);
        dconv_k<16, 16><<<g1(A3), THREADS, 0, stream>>>(P, S0, tw[22], tw[23], S2, H3, 7, SB, SB, SB);
        conv_k<16, 14, 3, true><<<g2(A3), THREADS, 0, stream>>>(S2, tw[10], c3d_b1, S1, H3, 7, SB, SB);
        conv_k<14, 12, 3, true><<<g2(A3), THREADS, 0, stream>>>(S1, tw[11], c3d_b2, S2, H3, 7, SB, SB);

        // ---- up path level 2 ----
        up2x_k<<<g1(12 * A2), THREADS, 0, stream>>>(S2, S0, 12 * A2, 16, 8, H3, SB, SB);
        conv_k<12, 12, 3, true><<<g2(A2), THREADS, 0, stream>>>(S0, tw[12], up2_b, S1, H2, 8, SB, SB);
        copy_k<<<g1(4 * A2), THREADS, 0, stream>>>((float4*)(S1 + 12 * A2), (const float4*)L2,
                                                   4 * A2, SB / 4, SB / 4);
        conv_k<28, 16, 3, true><<<g2(A2), THREADS, 0, stream>>>(S1, tw[13], c2u_b1, S0, H2, 8, SB, SB);
        conv_k<16, 8, 3, true><<<g2(A2), THREADS, 0, stream>>>(S0, tw[14], c2u_b2, S2, H2, 8, SB, SB);

        // ---- up path level 1 ----
        up2x_k<<<g1(8 * A1), THREADS, 0, stream>>>(S2, S0, 8 * A1, 18, 9, H2, SB, SB);
        conv_k<8, 8, 3, true><<<g2(A1), THREADS, 0, stream>>>(S0, tw[15], up1_b, S1, H1, 9, SB, SB);
        copy_k<<<g1(2 * A1), THREADS, 0, stream>>>((float4*)(S1 + 8 * A1), (const float4*)L1,
                                                   2 * A1, SB / 4, SB / 4);
        conv_k<16, 8, 3, true><<<g2(A1), THREADS, 0, stream>>>(S1, tw[16], c1u_b1, S0, H1, 9, SB, SB);
        conv_k<8, 2, 3, true><<<g2(A1), THREADS, 0, stream>>>(S0, tw[17], c1u_b2, outp, H1, 9, SB, obs);
    };

    for (int g = 0; g < 4; g += B)
        run_all(B, wsf + TW_FLOATS, SLOT,
                x + (size_t)g * 4 * A1, 4 * A1,
                out + (size_t)g * 2 * A1, 2 * A1);
}

// Round 5
// 2122.350 us; speedup vs baseline: 10.0083x; 4.1386x over previous
//
#include <hip/hip_runtime.h>
#include <math.h>

#define THREADS 256

__device__ __forceinline__ float silu_f(float v) {
    return v / (1.f + __expf(-v));
}

// ---------------------------------------------------------------------------
// Weight transpose: [co][ci][k2] -> [ci][k2][co]  (co contiguous)
// Also used per-group for deform-conv weights.
// ---------------------------------------------------------------------------
struct TEnt { const float* src; int dst; int cin; int cout; int k2; int base; int n; };
struct TTab { TEnt e[24]; int total; };

__global__ __launch_bounds__(THREADS)
void transpose_w_k(TTab t, float* __restrict__ tw) {
    const int i = blockIdx.x * THREADS + threadIdx.x;
    if (i >= t.total) return;
    int j = 0;
    while (i >= t.e[j].base + t.e[j].n) ++j;
    const TEnt e = t.e[j];
    const int local = i - e.base;
    const int co  = local % e.cout;
    const int tmp = local / e.cout;
    const int k   = tmp % e.k2;
    const int ci  = tmp / e.k2;
    tw[e.dst + local] = e.src[(co * e.cin + ci) * e.k2 + k];
}

// ---------------------------------------------------------------------------
// Direct conv2d, stride 1, pad (KS-1)/2, NCHW. PX=2 consecutive x-pixels per
// thread, all COUT channels in registers. Transposed weights staged into LDS
// in CCH-channel chunks, CO_S-padded so weight reads are float4 (b128)
// broadcasts. A sched_barrier(0) after EACH kx tap's FMA block stops the
// scheduler from hoisting weight vectors across the unrolled body (round-4
// lesson: unconstrained hoisting built ~900-float live ranges -> spill).
// ---------------------------------------------------------------------------
template<int CIN, int COUT, int KS, bool ACT, int CCH = CIN>
__global__ __launch_bounds__(THREADS)
void conv_k(const float* __restrict__ in, const float* __restrict__ wt,
            const float* __restrict__ bias, float* __restrict__ out,
            int H, int lw, int bs_in, int bs_out)
{
    constexpr int PAD = (KS - 1) / 2;
    constexpr int K2 = KS * KS;
    constexpr int PX = 2;
    constexpr int CO_S = (COUT + 3) & ~3;       // pad for 16B-aligned b128
    constexpr int NCH = CIN / CCH;
    __shared__ float sw[CCH * K2 * CO_S];

    const int W = 1 << lw;
    const int total = H << lw;
    const int idx = (blockIdx.x * THREADS + threadIdx.x) * PX;
    const float* ip0 = in + (size_t)blockIdx.y * bs_in;
    float* op = out + (size_t)blockIdx.y * bs_out;
    const int x0 = idx & (W - 1);               // even
    const int y  = idx >> lw;

    float acc[COUT][PX];
#pragma unroll
    for (int co = 0; co < COUT; ++co) {
        const float b = bias[co];
#pragma unroll
        for (int j = 0; j < PX; ++j) acc[co][j] = b;
    }

    for (int ch = 0; ch < NCH; ++ch) {
        const float* src = wt + (size_t)ch * (CCH * K2 * COUT);
        for (int i = threadIdx.x; i < CCH * K2 * COUT; i += THREADS) {
            const int co = i % COUT;
            const int rest = i / COUT;
            sw[rest * CO_S + co] = src[i];
        }
        __syncthreads();

#pragma unroll 1
        for (int cl = 0; cl < CCH; ++cl) {
            const float* __restrict__ row0 = ip0 + (size_t)(ch * CCH + cl) * total;
            // ---- load all KS input rows for this channel (static array) ----
            float r[KS][PX + KS - 1];
#pragma unroll
            for (int ky = 0; ky < KS; ++ky) {
                const int yy = y + ky - PAD;
                const bool vy = (unsigned)yy < (unsigned)H;
                const float* __restrict__ rp = row0 + (yy << lw);
                if (KS == 5) {
                    const bool vlo = vy && (x0 >= 2);
                    const bool vhi = vy && (x0 + 3 < W);
                    float2 a = make_float2(0.f, 0.f), b = a, c = a;
                    if (vlo) a = *reinterpret_cast<const float2*>(rp + x0 - 2);
                    if (vy)  b = *reinterpret_cast<const float2*>(rp + x0);
                    if (vhi) c = *reinterpret_cast<const float2*>(rp + x0 + 2);
                    r[ky][0] = a.x; r[ky][1] = a.y; r[ky][2] = b.x;
                    r[ky][3] = b.y; r[ky][4] = c.x; r[ky][5] = c.y;
                } else {
                    float2 b = make_float2(0.f, 0.f);
                    if (vy) b = *reinterpret_cast<const float2*>(rp + x0);
                    r[ky][1] = b.x; r[ky][2] = b.y;
                    r[ky][0] = (vy && x0 >= 1) ? rp[x0 - 1] : 0.f;
                    r[ky][3] = (vy && x0 + 2 < W) ? rp[x0 + 2] : 0.f;
                }
            }
            // ---- FMA sweep: one fenced region per (ky,kx) tap ----
#pragma unroll
            for (int ky = 0; ky < KS; ++ky) {
#pragma unroll
                for (int kx = 0; kx < KS; ++kx) {
                    const float4* __restrict__ wv =
                        reinterpret_cast<const float4*>(&sw[(cl * K2 + ky * KS + kx) * CO_S]);
#pragma unroll
                    for (int q = 0; q < CO_S / 4; ++q) {
                        const float4 w = wv[q];
                        const float wc[4] = {w.x, w.y, w.z, w.w};
#pragma unroll
                        for (int c = 0; c < 4; ++c) {
                            const int co = 4 * q + c;
                            if (co < COUT) {
#pragma unroll
                                for (int j = 0; j < PX; ++j)
                                    acc[co][j] = fmaf(r[ky][kx + j], wc[c], acc[co][j]);
                            }
                        }
                    }
                    __builtin_amdgcn_sched_barrier(0);   // pin live range per tap
                }
            }
        }
        if (NCH > 1) __syncthreads();
    }

#pragma unroll
    for (int co = 0; co < COUT; ++co) {
        float2 v;
        v.x = ACT ? silu_f(acc[co][0]) : acc[co][0];
        v.y = ACT ? silu_f(acc[co][1]) : acc[co][1];
        *reinterpret_cast<float2*>(op + (size_t)co * total + idx) = v;
    }
}

// ---------------------------------------------------------------------------
// DeformConv2d: 3x3, stride 1, pad 1, no bias. groups=2, offset groups=2.
// Per-group transposed weights [c][k][col] staged into LDS (b128 broadcast).
// offset layout: [OG=2][K=9][2(dy,dx)][H][W]
// ---------------------------------------------------------------------------
template<int CIN, int COUT>
__global__ __launch_bounds__(THREADS)
void dconv_k(const float* __restrict__ in, const float* __restrict__ off,
             const float* __restrict__ twg0, const float* __restrict__ twg1,
             float* __restrict__ out,
             int H, int lw, int bs_in, int bs_off, int bs_out)
{
    constexpr int K = 9;
    constexpr int OG = 2;
    constexpr int COG = CIN / OG;
    constexpr int COUTG = COUT / 2;
    constexpr int NWG = COG * K * COUTG;
    __shared__ float sw[2 * NWG];
    for (int i = threadIdx.x; i < 2 * NWG; i += THREADS)
        sw[i] = (i < NWG) ? twg0[i] : twg1[i - NWG];
    __syncthreads();

    const int W = 1 << lw;
    const int total = H << lw;
    const int idx = blockIdx.x * THREADS + threadIdx.x;
    const float* ip0 = in + (size_t)blockIdx.y * bs_in;
    const float* offp = off + (size_t)blockIdx.y * bs_off;
    float* op = out + (size_t)blockIdx.y * bs_out;
    const int x = idx & (W - 1);
    const int y = idx >> lw;

    float acc[COUT];
#pragma unroll
    for (int co = 0; co < COUT; ++co) acc[co] = 0.f;

#pragma unroll
    for (int og = 0; og < OG; ++og) {
#pragma unroll
        for (int k = 0; k < K; ++k) {
            const int ki = k / 3 - 1;
            const int kj = k % 3 - 1;
            const float dy = offp[(size_t)(((og * K + k) * 2 + 0)) * total + idx];
            const float dx = offp[(size_t)(((og * K + k) * 2 + 1)) * total + idx];
            const float py = dy + (float)(y + ki);
            const float px = dx + (float)(x + kj);
            const float y0f = floorf(py), x0f = floorf(px);
            const float ly = py - y0f, lx = px - x0f;
            const int y0 = (int)y0f, x0 = (int)x0f;
            const int y1 = y0 + 1, x1 = x0 + 1;
            const bool vy0 = (unsigned)y0 < (unsigned)H;
            const bool vy1 = (unsigned)y1 < (unsigned)H;
            const bool vx0 = (unsigned)x0 < (unsigned)W;
            const bool vx1 = (unsigned)x1 < (unsigned)W;
            const int cy0 = min(max(y0, 0), H - 1), cy1 = min(max(y1, 0), H - 1);
            const int cx0 = min(max(x0, 0), W - 1), cx1 = min(max(x1, 0), W - 1);
            const int i00 = (cy0 << lw) + cx0, i01 = (cy0 << lw) + cx1;
            const int i10 = (cy1 << lw) + cx0, i11 = (cy1 << lw) + cx1;
            const float f00 = (vy0 && vx0) ? (1.f - ly) * (1.f - lx) : 0.f;
            const float f01 = (vy0 && vx1) ? (1.f - ly) * lx : 0.f;
            const float f10 = (vy1 && vx0) ? ly * (1.f - lx) : 0.f;
            const float f11 = (vy1 && vx1) ? ly * lx : 0.f;
            const float* swg = &sw[og * NWG];
#pragma unroll
            for (int c = 0; c < COG; ++c) {
                const float* __restrict__ ip = ip0 + (size_t)(og * COG + c) * total;
                const float v = f00 * ip[i00] + f01 * ip[i01]
                              + f10 * ip[i10] + f11 * ip[i11];
                const float* __restrict__ wr = &swg[(c * K + k) * COUTG];
#pragma unroll
                for (int col = 0; col < COUTG; ++col)
                    acc[og * COUTG + col] = fmaf(v, wr[col], acc[og * COUTG + col]);
            }
        }
    }

#pragma unroll
    for (int co = 0; co < COUT; ++co)
        op[(size_t)co * total + idx] = acc[co];
}

// 2x2 average pool. n = C*Ho*Wo, lt = log2(Ho*Wo), lwo = log2(Wo).
__global__ __launch_bounds__(THREADS)
void avgpool_k(const float* __restrict__ in, float* __restrict__ out,
               int n, int lt, int lwo, int bsi, int bso)
{
    const int idx = blockIdx.x * THREADS + threadIdx.x;
    if (idx >= n) return;
    const float* ip0 = in + (size_t)blockIdx.y * bsi;
    float* op = out + (size_t)blockIdx.y * bso;
    const int c = idx >> lt;
    const int r = idx & ((1 << lt) - 1);
    const int oy = r >> lwo;
    const int ox = r & ((1 << lwo) - 1);
    const int Wi = 2 << lwo;
    const float* ip = ip0 + ((size_t)c << (lt + 2)) + ((size_t)(2 * oy) << (lwo + 1)) + 2 * ox;
    const float2 t = *reinterpret_cast<const float2*>(ip);
    const float2 b = *reinterpret_cast<const float2*>(ip + Wi);
    op[idx] = 0.25f * (t.x + t.y + b.x + b.y);
}

// Bilinear 2x upsample, align_corners=True.
__global__ __launch_bounds__(THREADS)
void up2x_k(const float* __restrict__ in, float* __restrict__ out,
            int n, int lt, int lwo, int Hin, int bsi, int bso)
{
    const int idx = blockIdx.x * THREADS + threadIdx.x;
    if (idx >= n) return;
    const float* ip0 = in + (size_t)blockIdx.y * bsi;
    float* op = out + (size_t)blockIdx.y * bso;
    const int c = idx >> lt;
    const int r = idx & ((1 << lt) - 1);
    const int oy = r >> lwo;
    const int ox = r & ((1 << lwo) - 1);
    const int W = 1 << (lwo - 1);
    const int H = Hin;
    const float s = (float)(H - 1) / (float)(2 * H - 1);
    const float fy = (float)oy * s;
    const float fx = (float)ox * s;
    const int y0 = (int)fy;
    const int x0 = (int)fx;
    const int y1 = min(y0 + 1, H - 1);
    const int x1 = min(x0 + 1, W - 1);
    const float wy = fy - (float)y0;
    const float wx = fx - (float)x0;
    const float* ip = ip0 + ((size_t)c << (lt - 2));
    const float v00 = ip[y0 * W + x0], v01 = ip[y0 * W + x1];
    const float v10 = ip[y1 * W + x0], v11 = ip[y1 * W + x1];
    op[idx] = (v00 * (1.f - wy) + v10 * wy) * (1.f - wx)
            + (v01 * (1.f - wy) + v11 * wy) * wx;
}

// strided batched d2d copy (float4 granularity)
__global__ __launch_bounds__(THREADS)
void copy_k(float4* __restrict__ dst, const float4* __restrict__ src,
            int n4, int bsd, int bss)
{
    const int i = blockIdx.x * THREADS + threadIdx.x;
    if (i >= n4) return;
    dst[(size_t)blockIdx.y * bsd + i] = src[(size_t)blockIdx.y * bss + i];
}

// ---------------------------------------------------------------------------

extern "C" void kernel_launch(void* const* d_in, const int* in_sizes, int n_in,
                              void* d_out, int out_size, void* d_ws, size_t ws_size,
                              hipStream_t stream) {
    const float* x      = (const float*)d_in[0];
    const float* eo1_b1 = (const float*)d_in[2];
    const float* eo1_b2 = (const float*)d_in[4];
    const float* c1d_b1 = (const float*)d_in[7];
    const float* c1d_b2 = (const float*)d_in[9];
    const float* eo2_b1 = (const float*)d_in[11];
    const float* eo2_b2 = (const float*)d_in[13];
    const float* c2d_b1 = (const float*)d_in[16];
    const float* c2d_b2 = (const float*)d_in[18];
    const float* eo3_b1 = (const float*)d_in[20];
    const float* eo3_b2 = (const float*)d_in[22];
    const float* c3d_b1 = (const float*)d_in[25];
    const float* c3d_b2 = (const float*)d_in[27];
    const float* up2_b  = (const float*)d_in[29];
    const float* c2u_b1 = (const float*)d_in[31];
    const float* c2u_b2 = (const float*)d_in[33];
    const float* up1_b  = (const float*)d_in[35];
    const float* c1u_b1 = (const float*)d_in[37];
    const float* c1u_b2 = (const float*)d_in[39];

    float* out = (float*)d_out;
    float* wsf = (float*)d_ws;

    constexpr int H1 = 512, A1 = H1 * H1;
    constexpr int H2 = 256, A2 = H2 * H2;
    constexpr int H3 = 128, A3 = H3 * H3;
    constexpr int TW_FLOATS = 81920;
    constexpr int SLOT = 70 * A1 + 24 * A2;

    // ---- transposed-weight table: 18 convs + 6 dconv groups ----
    const int widx[18]  = {1, 3, 6, 8, 10, 12, 15, 17, 19, 21, 24, 26, 28, 30, 32, 34, 36, 38};
    const int wcin[18]  = {4, 18, 2, 4, 8, 18, 8, 12, 16, 18, 16, 14, 12, 28, 16, 8, 16, 8};
    const int wcout[18] = {18, 36, 4, 8, 18, 36, 12, 16, 18, 36, 14, 12, 12, 16, 8, 8, 8, 2};
    const int wk2[18]   = {25, 25, 9, 9, 25, 25, 9, 9, 25, 25, 9, 9, 9, 9, 9, 9, 9, 9};
    TTab tab;
    const float* tw[24];
    int off = 0, base = 0;
    for (int i = 0; i < 18; ++i) {
        const int n = wcin[i] * wcout[i] * wk2[i];
        tab.e[i].src = (const float*)d_in[widx[i]];
        tab.e[i].dst = off; tab.e[i].cin = wcin[i]; tab.e[i].cout = wcout[i];
        tab.e[i].k2 = wk2[i]; tab.e[i].base = base; tab.e[i].n = n;
        tw[i] = wsf + off;
        off = (off + n + 63) & ~63;
        base += n;
    }
    const int didx[3]   = {5, 14, 23};
    const int dcoutg[3] = {1, 4, 8};
    const int dcpg[3]   = {2, 4, 8};
    for (int i = 0; i < 3; ++i) {
        for (int g = 0; g < 2; ++g) {
            const int e = 18 + 2 * i + g;
            const int n = dcoutg[i] * dcpg[i] * 9;
            tab.e[e].src = (const float*)d_in[didx[i]] + (size_t)g * n;
            tab.e[e].dst = off; tab.e[e].cin = dcpg[i]; tab.e[e].cout = dcoutg[i];
            tab.e[e].k2 = 9; tab.e[e].base = base; tab.e[e].n = n;
            tw[e] = wsf + off;
            off = (off + n + 63) & ~63;
            base += n;
        }
    }
    tab.total = base;
    transpose_w_k<<<(base + THREADS - 1) / THREADS, THREADS, 0, stream>>>(tab, wsf);

    int B = 4;
    while (B > 1 && ws_size < ((size_t)TW_FLOATS + (size_t)B * SLOT) * sizeof(float)) B >>= 1;

    auto run_all = [&](int Bc, float* slot, int SB,
                       const float* xin, int xbs, float* outp, int obs) {
        float* S0 = slot;                // 36*A1
        float* S1 = S0 + 36 * A1;        // 18*A1
        float* S2 = S1 + 18 * A1;        //  8*A1
        float* P  = S2 + 8 * A1;         //  8*A2
        float* L1 = P + 8 * A2;          //  8*A1  (conv1_d skip)
        float* L2 = L1 + 8 * A1;         // 16*A2  (conv2_d skip)
        auto g2 = [&](int n) { return dim3((n + 2 * THREADS - 1) / (2 * THREADS), Bc); };
        auto g1 = [&](int n) { return dim3((n + THREADS - 1) / THREADS, Bc); };

        // ---- level 1 down ----
        conv_k<4, 18, 5, false><<<g2(A1), THREADS, 0, stream>>>(xin, tw[0], eo1_b1, S1, H1, 9, xbs, SB);
        conv_k<18, 36, 5, false, 6><<<g2(A1), THREADS, 0, stream>>>(S1, tw[1], eo1_b2, S0, H1, 9, SB, SB);
        dconv_k<4, 2><<<g1(A1), THREADS, 0, stream>>>(xin, S0, tw[18], tw[19], S2, H1, 9, xbs, SB, SB);
        conv_k<2, 4, 3, true><<<g2(A1), THREADS, 0, stream>>>(S2, tw[2], c1d_b1, S1, H1, 9, SB, SB);
        conv_k<4, 8, 3, true><<<g2(A1), THREADS, 0, stream>>>(S1, tw[3], c1d_b2, L1, H1, 9, SB, SB);
        avgpool_k<<<g1(8 * A2), THREADS, 0, stream>>>(L1, P, 8 * A2, 16, 8, SB, SB);

        // ---- level 2 down ----
        conv_k<8, 18, 5, false><<<g2(A2), THREADS, 0, stream>>>(P, tw[4], eo2_b1, S1, H2, 8, SB, SB);
        conv_k<18, 36, 5, false, 6><<<g2(A2), THREADS, 0, stream>>>(S1, tw[5], eo2_b2, S0, H2, 8, SB, SB);
        dconv_k<8, 8><<<g1(A2), THREADS, 0, stream>>>(P, S0, tw[20], tw[21], S2, H2, 8, SB, SB, SB);
        conv_k<8, 12, 3, true><<<g2(A2), THREADS, 0, stream>>>(S2, tw[6], c2d_b1, S1, H2, 8, SB, SB);
        conv_k<12, 16, 3, true><<<g2(A2), THREADS, 0, stream>>>(S1, tw[7], c2d_b2, L2, H2, 8, SB, SB);
        avgpool_k<<<g1(16 * A3), THREADS, 0, stream>>>(L2, P, 16 * A3, 14, 7, SB, SB);

        // ---- level 3 (bottleneck) ----
        conv_k<16, 18, 5, false, 8><<<g2(A3), THREADS, 0, stream>>>(P, tw[8], eo3_b1, S1, H3, 7, SB, SB);
        conv_k<18, 36, 5, false, 6><<<g2(A3), THREADS, 0, stream>>>(S1, tw[9], eo3_b2, S0, H3, 7, SB, SB);
        dconv_k<16, 16><<<g1(A3), THREADS, 0, stream>>>(P, S0, tw[22], tw[23], S2, H3, 7, SB, SB, SB);
        conv_k<16, 14, 3, true><<<g2(A3), THREADS, 0, stream>>>(S2, tw[10], c3d_b1, S1, H3, 7, SB, SB);
        conv_k<14, 12, 3, true><<<g2(A3), THREADS, 0, stream>>>(S1, tw[11], c3d_b2, S2, H3, 7, SB, SB);

        // ---- up path level 2 ----
        up2x_k<<<g1(12 * A2), THREADS, 0, stream>>>(S2, S0, 12 * A2, 16, 8, H3, SB, SB);
        conv_k<12, 12, 3, true><<<g2(A2), THREADS, 0, stream>>>(S0, tw[12], up2_b, S1, H2, 8, SB, SB);
        copy_k<<<g1(4 * A2), THREADS, 0, stream>>>((float4*)(S1 + 12 * A2), (const float4*)L2,
                                                   4 * A2, SB / 4, SB / 4);
        conv_k<28, 16, 3, true><<<g2(A2), THREADS, 0, stream>>>(S1, tw[13], c2u_b1, S0, H2, 8, SB, SB);
        conv_k<16, 8, 3, true><<<g2(A2), THREADS, 0, stream>>>(S0, tw[14], c2u_b2, S2, H2, 8, SB, SB);

        // ---- up path level 1 ----
        up2x_k<<<g1(8 * A1), THREADS, 0, stream>>>(S2, S0, 8 * A1, 18, 9, H2, SB, SB);
        conv_k<8, 8, 3, true><<<g2(A1), THREADS, 0, stream>>>(S0, tw[15], up1_b, S1, H1, 9, SB, SB);
        copy_k<<<g1(2 * A1), THREADS, 0, stream>>>((float4*)(S1 + 8 * A1), (const float4*)L1,
                                                   2 * A1, SB / 4, SB / 4);
        conv_k<16, 8, 3, true><<<g2(A1), THREADS, 0, stream>>>(S1, tw[16], c1u_b1, S0, H1, 9, SB, SB);
        conv_k<8, 2, 3, true><<<g2(A1), THREADS, 0, stream>>>(S0, tw[17], c1u_b2, outp, H1, 9, SB, obs);
    };

    for (int g = 0; g < 4; g += B)
        run_all(B, wsf + TW_FLOATS, SLOT,
                x + (size_t)g * 4 * A1, 4 * A1,
                out + (size_t)g * 2 * A1, 2 * A1);
}